// Round 8
// baseline (334.460 us; speedup 1.0000x reference)
//
#include <hip/hip_runtime.h>
#include <hip/hip_bf16.h>

// Problem constants
#define DD   256
#define DD3  768
#define NB   128
#define NE   7      // 1 pos_u + 1 pos_v + 5 neg embeddings

// Workspace layout (float offsets)
#define OFF_TVT  0u          // tv transposed [256 i][128 b]
#define OFF_TVB  32768u      // tvB [128 b][256 j]
#define OFF_EMBT 65536u      // embT [7 e][768 k][128 b] fp32 (688128 floats, ends at OFF_H3)
#define OFF_H3   753664u     // h3  [128 b][7 e][256 j]  (atomic-accumulated, zeroed per call)
#define OFF_G    983040u     // G = W4^T W4 [256][256]
#define OFF_GV   1048576u    // g = W4^T b4 [256]
#define OFF_SC   1048832u    // tvf (bf16 frags) aliased with scoreb/negb (tvf dead by k_score)
#define OFF_TF   1065216u    // Tf bf16 A-fragments (100.7 MB); ws proven >= 105.7 MB

// Fragment linear index: FI = j*24576 + kc*4096 + it*512 + mh*256 + mf*64 + l
// Frag content: lane l, elem jj (bf16x8) = T[i = it*32 + (l>>4)*8 + jj][j][k = kc*128 + mh*64 + mf*16 + (l&15)]

typedef __attribute__((ext_vector_type(8))) short bf16x8;
typedef __attribute__((ext_vector_type(4))) float f32x4;

__device__ __forceinline__ unsigned bf16rne(float f) {
  unsigned u = __float_as_uint(f);
  return (u + 0x7fffu + ((u >> 16) & 1u)) >> 16;   // round-to-nearest-even
}

// ---------------------------------------------------------------------------
__global__ void k_setup(const float* __restrict__ timev,
                        const float* __restrict__ m1,
                        const float* __restrict__ b1,
                        const float* __restrict__ W2,
                        const float* __restrict__ b2,
                        const float* __restrict__ Bm,
                        float* __restrict__ tv_t,
                        float* __restrict__ tvB) {
  const int b = blockIdx.x, i = threadIdx.x;
  __shared__ float h1[DD];
  __shared__ float tvs[DD];
  const float t = timev[b] * (1.0f / 20.0f);
  h1[i] = tanhf(fmaf(t, m1[i], b1[i]));
  __syncthreads();
  float acc = b2[i];
  const float* w2r = W2 + i * DD;
#pragma unroll 8
  for (int jj = 0; jj < DD; ++jj) acc = fmaf(h1[jj], w2r[jj], acc);
  const float tvi = tanhf(acc);
  tvs[i] = tvi;
  tv_t[i * NB + b] = tvi;
  __syncthreads();
  float a2 = 0.f;
#pragma unroll 8
  for (int ii = 0; ii < DD; ++ii) a2 = fmaf(tvs[ii], Bm[ii * DD + i], a2);
  tvB[b * DD + i] = a2;
}

// ---------------------------------------------------------------------------
// Pack tv into bf16 MFMA B-fragments: frag f = bf*8+it (bf = b-frag 0..7)
__global__ void k_pack(const float* __restrict__ tv_t, short* __restrict__ tvf) {
  const int t = blockIdx.x * 256 + threadIdx.x;   // 4096 threads
  const int f = t >> 6, l = t & 63;
  const int b = (f >> 3) * 16 + (l & 15);
  const int i0 = (f & 7) * 32 + ((l >> 4) & 3) * 8;
  bf16x8 v;
#pragma unroll
  for (int jj = 0; jj < 8; ++jj)
    v[jj] = (short)bf16rne(tv_t[(i0 + jj) * NB + b]);
  *(bf16x8*)(tvf + (long)t * 8) = v;
}

// ---------------------------------------------------------------------------
// Fused gather+transpose: embT[e][k][b] = {U|V}[idx(e,b)][k].
__global__ __launch_bounds__(256) void k_embT(const int* __restrict__ pos_u,
                                              const int* __restrict__ pos_v,
                                              const int* __restrict__ neg_v,
                                              const float* __restrict__ U,
                                              const float* __restrict__ V,
                                              float* __restrict__ embT) {
  __shared__ float Ls[64 * 133];
  const int e = blockIdx.x / 12, kt = blockIdx.x % 12;
  const int t = threadIdx.x;
#pragma unroll 1
  for (int rep = 0; rep < 8; ++rep) {
    const int idx = rep * 256 + t;
    const int b = idx >> 4, f4 = idx & 15;
    int row;
    if (e == 0)      row = pos_u[b];
    else if (e == 1) row = pos_v[b];
    else             row = neg_v[b * 5 + (e - 2)];
    const float* src = (e == 0) ? U : V;
    const float4 v = *(const float4*)(src + (long)row * DD3 + kt * 64 + f4 * 4);
    Ls[(f4 * 4 + 0) * 133 + b] = v.x;
    Ls[(f4 * 4 + 1) * 133 + b] = v.y;
    Ls[(f4 * 4 + 2) * 133 + b] = v.z;
    Ls[(f4 * 4 + 3) * 133 + b] = v.w;
  }
  __syncthreads();
#pragma unroll 1
  for (int rep = 0; rep < 8; ++rep) {
    const int idx = rep * 256 + t;
    const int k = idx >> 5, fb = idx & 31;
    float4 o;
    o.x = Ls[k * 133 + fb * 4 + 0];
    o.y = Ls[k * 133 + fb * 4 + 1];
    o.z = Ls[k * 133 + fb * 4 + 2];
    o.w = Ls[k * 133 + fb * 4 + 3];
    *(float4*)(embT + ((long)e * DD3 + kt * 64 + k) * NB + fb * 4) = o;
  }
}

// ---------------------------------------------------------------------------
__global__ __launch_bounds__(1024) void k_gram(const float* __restrict__ W4,
                                               const float* __restrict__ b4,
                                               float* __restrict__ G,
                                               float* __restrict__ gv) {
  const int p = blockIdx.x, t = threadIdx.x;
  const int q = t & 255, nq = t >> 8;
  __shared__ float colp[DD3];
  __shared__ float red[4][257];
  __shared__ float gred[4];
  for (int n = t; n < DD3; n += 1024) colp[n] = W4[n * DD + p];
  __syncthreads();
  float acc = 0.f;
  const int n0 = nq * 192;
#pragma unroll 8
  for (int n = n0; n < n0 + 192; ++n) acc = fmaf(colp[n], W4[n * DD + q], acc);
  red[nq][q] = acc;
  float gp = 0.f;
  for (int n = n0; n < n0 + 192; ++n) gp = fmaf(b4[n], colp[n], gp);
  if (q == 0) gred[nq] = gp;
  __syncthreads();
  if (t < 256) G[p * DD + t] = red[0][t] + red[1][t] + red[2][t] + red[3][t];
  if (t == 0) gv[p] = gred[0] + gred[1] + gred[2] + gred[3];
}

// ---------------------------------------------------------------------------
// Repack T (fp32, [i][j][k]) -> Tf (bf16 A-fragments, lane-final order).
__global__ __launch_bounds__(512) void k_repack(const float* __restrict__ T,
                                                short* __restrict__ Tf) {
  __shared__ float Ls[16 * 772];
  const int it = blockIdx.x >> 7;
  const int jp = blockIdx.x & 127;
  const int j0 = jp * 2;
  const int t = threadIdx.x;
  const int w = t >> 6, lane = t & 63;

#pragma unroll 1
  for (int l4 = 0; l4 < 4; ++l4) {
    const int i = it * 32 + l4 * 8 + w;
    float4 v[2][3];
#pragma unroll
    for (int jl = 0; jl < 2; ++jl) {
      const float4* src = (const float4*)(T + (long)i * 196608 + (j0 + jl) * 768);
#pragma unroll
      for (int c = 0; c < 3; ++c) v[jl][c] = src[c * 64 + lane];
    }
#pragma unroll
    for (int jl = 0; jl < 2; ++jl) {
      const int row = w * 2 + jl;
#pragma unroll
      for (int c = 0; c < 3; ++c)
        *(float4*)&Ls[row * 772 + (c * 64 + lane) * 4] = v[jl][c];
    }
    __syncthreads();
#pragma unroll
    for (int q = 0; q < 3; ++q) {
      const int F = t + 512 * q;
      const int l15 = F & 15;
      const int mf = (F >> 4) & 3;
      const int mh = (F >> 6) & 1;
      const int jc = F >> 7;
      const int kc = jc % 6;
      const int jl = jc / 6;
      const int k = kc * 128 + mh * 64 + mf * 16 + l15;
      bf16x8 o;
#pragma unroll
      for (int jj = 0; jj < 8; ++jj)
        o[jj] = (short)bf16rne(Ls[(jj * 2 + jl) * 772 + k]);
      const long FI = (long)(j0 + jl) * 24576 + kc * 4096 + it * 512 +
                      mh * 256 + mf * 64 + l4 * 16 + l15;
      *(bf16x8*)(Tf + FI * 8) = o;
    }
    __syncthreads();
  }
}

// ---------------------------------------------------------------------------
// Main kernel v2 (UNCHANGED from R7 for clean comparison).
__global__ __launch_bounds__(512, 3) void k_main_f(const short* __restrict__ Tf,
                                                   const short* __restrict__ tvf,
                                                   const float* __restrict__ embT,
                                                   const float* __restrict__ tvB,
                                                   float* __restrict__ h3) {
  __shared__ float h3red[NB][NE];
  const int bid = blockIdx.x;
  const int j = bid & 255;
  const int kc = bid >> 8;

  const int t = threadIdx.x;
  const int l = t & 63;
  const int w = t >> 6;
  const int bq = w >> 1;             // 0..3 (32 b each)
  const int mh = w & 1;              // k-half of the 128-k chunk
  const int l15 = l & 15;
  const int l4 = (l >> 4) & 3;

  const bf16x8* fr  = (const bf16x8*)Tf + ((long)j * 24576 + kc * 4096 + mh * 256 + l);
  const bf16x8* tvp = (const bf16x8*)tvf + l;

  f32x4 acc[4][2];
#pragma unroll
  for (int mf = 0; mf < 4; ++mf) {
    acc[mf][0] = {0.f, 0.f, 0.f, 0.f};
    acc[mf][1] = {0.f, 0.f, 0.f, 0.f};
  }

  bf16x8 afb[2][4];
  bf16x8 tvb[2][2];
#pragma unroll
  for (int mf = 0; mf < 4; ++mf) afb[0][mf] = fr[mf * 64];
#pragma unroll
  for (int nf = 0; nf < 2; ++nf) tvb[0][nf] = tvp[((bq * 2 + nf) * 8) * 64];

#pragma unroll
  for (int it = 0; it < 8; ++it) {
    const int cur = it & 1, nxt = cur ^ 1;
    if (it < 7) {
#pragma unroll
      for (int mf = 0; mf < 4; ++mf) afb[nxt][mf] = fr[(it + 1) * 512 + mf * 64];
#pragma unroll
      for (int nf = 0; nf < 2; ++nf) tvb[nxt][nf] = tvp[((bq * 2 + nf) * 8 + it + 1) * 64];
    }
#pragma unroll
    for (int mf = 0; mf < 4; ++mf) {
      acc[mf][0] = __builtin_amdgcn_mfma_f32_16x16x32_bf16(afb[cur][mf], tvb[cur][0], acc[mf][0], 0, 0, 0);
      acc[mf][1] = __builtin_amdgcn_mfma_f32_16x16x32_bf16(afb[cur][mf], tvb[cur][1], acc[mf][1], 0, 0, 0);
    }
  }

  float h3p[NE][2];
#pragma unroll
  for (int e = 0; e < NE; ++e) { h3p[e][0] = 0.f; h3p[e][1] = 0.f; }

  const float* et = embT + (long)(kc * 128 + mh * 64 + l4 * 4) * NB + bq * 32 + l15;
#pragma unroll
  for (int mf = 0; mf < 4; ++mf) {
#pragma unroll
    for (int q = 0; q < 4; ++q) {
      const int kro = (mf * 16 + q) * NB;
      float v[NE][2];
#pragma unroll
      for (int e = 0; e < NE; ++e) {
        v[e][0] = et[(long)e * 98304 + kro];
        v[e][1] = et[(long)e * 98304 + kro + 16];
      }
#pragma unroll
      for (int e = 0; e < NE; ++e) {
        h3p[e][0] = fmaf(acc[mf][0][q], v[e][0], h3p[e][0]);
        h3p[e][1] = fmaf(acc[mf][1][q], v[e][1], h3p[e][1]);
      }
    }
  }

  float hr[NE][2];
#pragma unroll
  for (int e = 0; e < NE; ++e)
#pragma unroll
    for (int nf = 0; nf < 2; ++nf) {
      float v = h3p[e][nf];
      v += __shfl_xor(v, 16);
      v += __shfl_xor(v, 32);
      hr[e][nf] = v;
    }
  __syncthreads();
  if (mh == 0 && l < 16) {
#pragma unroll
    for (int e = 0; e < NE; ++e) {
      h3red[bq * 32 + l][e]      = hr[e][0];
      h3red[bq * 32 + 16 + l][e] = hr[e][1];
    }
  }
  __syncthreads();
  if (mh == 1 && l < 16) {
#pragma unroll
    for (int nf = 0; nf < 2; ++nf) {
      const int b = bq * 32 + nf * 16 + l;
      const float tb = (kc == 0) ? tvB[b * DD + j] : 0.f;
#pragma unroll
      for (int e = 0; e < NE; ++e)
        atomicAdd(&h3[((long)b * NE + e) * DD + j], h3red[b][e] + hr[e][nf] + tb);
    }
  }
}

// ---------------------------------------------------------------------------
// ABLATION A: Tf-stream + MFMA loop ONLY (no epilogue, no writes).
// acc kept alive via empty asm (prevents DCE of loads+MFMA).
__global__ __launch_bounds__(512, 3) void k_abl_main(const short* __restrict__ Tf,
                                                     const short* __restrict__ tvf) {
  const int bid = blockIdx.x;
  const int j = bid & 255;
  const int kc = bid >> 8;
  const int t = threadIdx.x;
  const int l = t & 63;
  const int w = t >> 6;
  const int bq = w >> 1;
  const int mh = w & 1;

  const bf16x8* fr  = (const bf16x8*)Tf + ((long)j * 24576 + kc * 4096 + mh * 256 + l);
  const bf16x8* tvp = (const bf16x8*)tvf + l;

  f32x4 acc[4][2];
#pragma unroll
  for (int mf = 0; mf < 4; ++mf) {
    acc[mf][0] = {0.f, 0.f, 0.f, 0.f};
    acc[mf][1] = {0.f, 0.f, 0.f, 0.f};
  }
  bf16x8 afb[2][4];
  bf16x8 tvb[2][2];
#pragma unroll
  for (int mf = 0; mf < 4; ++mf) afb[0][mf] = fr[mf * 64];
#pragma unroll
  for (int nf = 0; nf < 2; ++nf) tvb[0][nf] = tvp[((bq * 2 + nf) * 8) * 64];

#pragma unroll
  for (int it = 0; it < 8; ++it) {
    const int cur = it & 1, nxt = cur ^ 1;
    if (it < 7) {
#pragma unroll
      for (int mf = 0; mf < 4; ++mf) afb[nxt][mf] = fr[(it + 1) * 512 + mf * 64];
#pragma unroll
      for (int nf = 0; nf < 2; ++nf) tvb[nxt][nf] = tvp[((bq * 2 + nf) * 8 + it + 1) * 64];
    }
#pragma unroll
    for (int mf = 0; mf < 4; ++mf) {
      acc[mf][0] = __builtin_amdgcn_mfma_f32_16x16x32_bf16(afb[cur][mf], tvb[cur][0], acc[mf][0], 0, 0, 0);
      acc[mf][1] = __builtin_amdgcn_mfma_f32_16x16x32_bf16(afb[cur][mf], tvb[cur][1], acc[mf][1], 0, 0, 0);
    }
  }
#pragma unroll
  for (int mf = 0; mf < 4; ++mf)
#pragma unroll
    for (int nf = 0; nf < 2; ++nf)
#pragma unroll
      for (int q = 0; q < 4; ++q)
        asm volatile("" :: "v"(acc[mf][nf][q]));
}

// ---------------------------------------------------------------------------
// ABLATION B: epilogue + reduce + atomics ONLY. acc seeded from runtime zp
// (opaque zero); atomic adds value*zp == +0.0f -> h3 unchanged, traffic identical.
__global__ __launch_bounds__(512, 3) void k_abl_epi(const float* __restrict__ embT,
                                                    const float* __restrict__ tvB,
                                                    float* __restrict__ h3,
                                                    float zp) {
  __shared__ float h3red[NB][NE];
  const int bid = blockIdx.x;
  const int j = bid & 255;
  const int kc = bid >> 8;
  const int t = threadIdx.x;
  const int l = t & 63;
  const int w = t >> 6;
  const int bq = w >> 1;
  const int mh = w & 1;
  const int l15 = l & 15;
  const int l4 = (l >> 4) & 3;

  f32x4 acc[4][2];
#pragma unroll
  for (int mf = 0; mf < 4; ++mf) {
    acc[mf][0] = {zp, zp, zp, zp};
    acc[mf][1] = {zp, zp, zp, zp};
  }

  float h3p[NE][2];
#pragma unroll
  for (int e = 0; e < NE; ++e) { h3p[e][0] = 0.f; h3p[e][1] = 0.f; }

  const float* et = embT + (long)(kc * 128 + mh * 64 + l4 * 4) * NB + bq * 32 + l15;
#pragma unroll
  for (int mf = 0; mf < 4; ++mf) {
#pragma unroll
    for (int q = 0; q < 4; ++q) {
      const int kro = (mf * 16 + q) * NB;
      float v[NE][2];
#pragma unroll
      for (int e = 0; e < NE; ++e) {
        v[e][0] = et[(long)e * 98304 + kro];
        v[e][1] = et[(long)e * 98304 + kro + 16];
      }
#pragma unroll
      for (int e = 0; e < NE; ++e) {
        h3p[e][0] = fmaf(acc[mf][0][q], v[e][0], h3p[e][0]);
        h3p[e][1] = fmaf(acc[mf][1][q], v[e][1], h3p[e][1]);
      }
    }
  }

  float hr[NE][2];
#pragma unroll
  for (int e = 0; e < NE; ++e)
#pragma unroll
    for (int nf = 0; nf < 2; ++nf) {
      float v = h3p[e][nf];
      v += __shfl_xor(v, 16);
      v += __shfl_xor(v, 32);
      hr[e][nf] = v;
    }
  __syncthreads();
  if (mh == 0 && l < 16) {
#pragma unroll
    for (int e = 0; e < NE; ++e) {
      h3red[bq * 32 + l][e]      = hr[e][0];
      h3red[bq * 32 + 16 + l][e] = hr[e][1];
    }
  }
  __syncthreads();
  if (mh == 1 && l < 16) {
#pragma unroll
    for (int nf = 0; nf < 2; ++nf) {
      const int b = bq * 32 + nf * 16 + l;
      const float tb = (kc == 0) ? tvB[b * DD + j] : 0.f;
#pragma unroll
      for (int e = 0; e < NE; ++e)
        atomicAdd(&h3[((long)b * NE + e) * DD + j], (h3red[b][e] + hr[e][nf] + tb) * zp);
    }
  }
}

// ---------------------------------------------------------------------------
__global__ void k_score(const float* __restrict__ h3,
                        const float* __restrict__ G,
                        const float* __restrict__ gv,
                        const float* __restrict__ b4,
                        float* __restrict__ scoreb,
                        float* __restrict__ negb) {
  const int b = blockIdx.x, t = threadIdx.x;
  __shared__ float h3s[NE * DD];
  __shared__ float red[4][16];
  for (int idx = t; idx < NE * DD; idx += 256) h3s[idx] = h3[(long)b * NE * DD + idx];
  __syncthreads();
  float racc = 0.f;
#pragma unroll 8
  for (int jp = 0; jp < DD; ++jp) racc = fmaf(G[jp * DD + t], h3s[jp], racc);

  float loc[14];
#pragma unroll
  for (int e = 1; e < NE; ++e) loc[e - 1] = racc * h3s[e * DD + t];
  loc[6] = gv[t] * h3s[t];
#pragma unroll
  for (int e = 1; e < NE; ++e) loc[6 + e] = gv[t] * h3s[e * DD + t];
  loc[13] = b4[t] * b4[t] + b4[t + 256] * b4[t + 256] + b4[t + 512] * b4[t + 512];

  const int lane = t & 63, wid = t >> 6;
#pragma unroll
  for (int qd = 0; qd < 14; ++qd) {
    float v = loc[qd];
#pragma unroll
    for (int m = 1; m < 64; m <<= 1) v += __shfl_xor(v, m);
    if (lane == 0) red[wid][qd] = v;
  }
  __syncthreads();
  if (t == 0) {
    float r[14];
#pragma unroll
    for (int qd = 0; qd < 14; ++qd)
      r[qd] = red[0][qd] + red[1][qd] + red[2][qd] + red[3][qd];
    const float c = r[13], gu = r[6];
    auto logsig = [](float x) { return fminf(x, 0.f) - log1pf(expf(-fabsf(x))); };
    float dv = r[0] + gu + r[7] + c;
    dv = fminf(fmaxf(dv, -10.f), 10.f);
    const float sc = -logsig(dv);
    float ns = 0.f;
    for (int lx = 1; lx < 6; ++lx) {
      float dn = r[lx] + gu + r[7 + lx] + c;
      dn = fminf(fmaxf(dn, -10.f), 10.f);
      ns -= logsig(-dn);
    }
    scoreb[b] = sc;
    negb[b] = ns * 0.2f;
  }
}

// ---------------------------------------------------------------------------
__global__ void k_final(const float* __restrict__ scoreb,
                        const float* __restrict__ negb,
                        float* __restrict__ out) {
  const int t = threadIdx.x;
  float s = scoreb[t], n = negb[t];
#pragma unroll
  for (int m = 1; m < 64; m <<= 1) {
    s += __shfl_xor(s, m);
    n += __shfl_xor(n, m);
  }
  __shared__ float rs[2], rn[2];
  if ((t & 63) == 0) { rs[t >> 6] = s; rn[t >> 6] = n; }
  __syncthreads();
  if (t == 0) {
    const float S = (rs[0] + rs[1]) * (1.0f / 128.0f);
    const float N = (rn[0] + rn[1]) * (1.0f / 128.0f);
    out[0] = S + N;
    out[1] = S;
    out[2] = N;
  }
}

// ---------------------------------------------------------------------------
extern "C" void kernel_launch(void* const* d_in, const int* in_sizes, int n_in,
                              void* d_out, int out_size, void* d_ws, size_t ws_size,
                              hipStream_t stream) {
  const int*   pos_u = (const int*)d_in[0];
  const int*   pos_v = (const int*)d_in[1];
  const int*   neg_v = (const int*)d_in[2];
  const float* timev = (const float*)d_in[3];
  const float* m1    = (const float*)d_in[4];
  const float* b1    = (const float*)d_in[5];
  const float* W2    = (const float*)d_in[6];
  const float* b2    = (const float*)d_in[7];
  const float* W4    = (const float*)d_in[8];
  const float* b4    = (const float*)d_in[9];
  const float* U     = (const float*)d_in[10];
  const float* V     = (const float*)d_in[11];
  const float* T     = (const float*)d_in[12];
  const float* Bm    = (const float*)d_in[13];

  float* ws     = (float*)d_ws;
  float* tv_t   = ws + OFF_TVT;
  float* tvB    = ws + OFF_TVB;
  float* embT   = ws + OFF_EMBT;
  float* h3     = ws + OFF_H3;
  float* G      = ws + OFF_G;
  float* gv     = ws + OFF_GV;
  short* tvf    = (short*)(ws + OFF_SC);
  short* Tf     = (short*)(ws + OFF_TF);
  float* scoreb = ws + OFF_SC;
  float* negb   = ws + OFF_SC + 128;
  float* out    = (float*)d_out;

  hipMemsetAsync(h3, 0, (size_t)NB * NE * DD * sizeof(float), stream);
  k_setup<<<128, 256, 0, stream>>>(timev, m1, b1, W2, b2, Bm, tv_t, tvB);
  k_pack<<<16, 256, 0, stream>>>(tv_t, tvf);
  k_embT<<<84, 256, 0, stream>>>(pos_u, pos_v, neg_v, U, V, embT);
  k_gram<<<256, 1024, 0, stream>>>(W4, b4, G, gv);
  k_repack<<<1024, 512, 0, stream>>>(T, Tf);
  k_main_f<<<1536, 512, 0, stream>>>(Tf, tvf, embT, tvB, h3);
  k_score<<<128, 256, 0, stream>>>(h3, G, gv, b4, scoreb, negb);
  k_final<<<1, 128, 0, stream>>>(scoreb, negb, out);
  // --- diagnostic ablations (after outputs are final; h3 perturbed by +0.0 only)
  k_abl_main<<<1536, 512, 0, stream>>>(Tf, tvf);
  k_abl_epi<<<1536, 512, 0, stream>>>(embT, tvB, h3, 0.0f);
}

// Round 9
// 306.934 us; speedup vs baseline: 1.0897x; 1.0897x over previous
//
#include <hip/hip_runtime.h>
#include <hip/hip_bf16.h>

// Problem constants
#define DD   256
#define DD3  768
#define NB   128
#define NE   7      // 1 pos_u + 1 pos_v + 5 neg embeddings

// Workspace layout (float offsets)
#define OFF_TVT  0u          // tv transposed [256 i][128 b]
#define OFF_TVB  32768u      // tvB [128 b][256 j]
#define OFF_EMB  65536u      // emb [7 e][128 b][768 k] fp32
#define OFF_H3   753664u     // h3  [128 b][7 e][256 j]  (atomic-accumulated, zeroed per call)
#define OFF_G    983040u     // G = W4^T W4 [256][256]
#define OFF_GV   1048576u    // g = W4^T b4 [256]
#define OFF_SC   1048832u    // tvf (bf16 frags) aliased with scoreb/negb (tvf dead by k_score)
#define OFF_TF   1065216u    // Tf bf16 A-fragments (100.7 MB); ws proven >= 105 MB (R7 ran unconditionally)

// Fragment linear index: FI = j*24576 + kc*4096 + it*512 + mh*256 + mf*64 + l
// Frag content: lane l, elem jj (bf16x8) = T[i = it*32 + (l>>4)*8 + jj][j][k = kc*128 + mh*64 + mf*16 + (l&15)]

typedef __attribute__((ext_vector_type(8))) short bf16x8;
typedef __attribute__((ext_vector_type(4))) float f32x4;

__device__ __forceinline__ unsigned bf16rne(float f) {
  unsigned u = __float_as_uint(f);
  return (u + 0x7fffu + ((u >> 16) & 1u)) >> 16;   // round-to-nearest-even
}

// ---------------------------------------------------------------------------
__global__ void k_setup(const float* __restrict__ timev,
                        const float* __restrict__ m1,
                        const float* __restrict__ b1,
                        const float* __restrict__ W2,
                        const float* __restrict__ b2,
                        const float* __restrict__ Bm,
                        float* __restrict__ tv_t,
                        float* __restrict__ tvB) {
  const int b = blockIdx.x, i = threadIdx.x;
  __shared__ float h1[DD];
  __shared__ float tvs[DD];
  const float t = timev[b] * (1.0f / 20.0f);
  h1[i] = tanhf(fmaf(t, m1[i], b1[i]));
  __syncthreads();
  float acc = b2[i];
  const float* w2r = W2 + i * DD;
#pragma unroll 8
  for (int jj = 0; jj < DD; ++jj) acc = fmaf(h1[jj], w2r[jj], acc);
  const float tvi = tanhf(acc);
  tvs[i] = tvi;
  tv_t[i * NB + b] = tvi;
  __syncthreads();
  float a2 = 0.f;
#pragma unroll 8
  for (int ii = 0; ii < DD; ++ii) a2 = fmaf(tvs[ii], Bm[ii * DD + i], a2);
  tvB[b * DD + i] = a2;
}

// ---------------------------------------------------------------------------
// Pack tv into bf16 MFMA B-fragments: frag f = bf*8+it (bf = b-frag 0..7)
__global__ void k_pack(const float* __restrict__ tv_t, short* __restrict__ tvf) {
  const int t = blockIdx.x * 256 + threadIdx.x;   // 4096 threads
  const int f = t >> 6, l = t & 63;
  const int b = (f >> 3) * 16 + (l & 15);
  const int i0 = (f & 7) * 32 + ((l >> 4) & 3) * 8;
  bf16x8 v;
#pragma unroll
  for (int jj = 0; jj < 8; ++jj)
    v[jj] = (short)bf16rne(tv_t[(i0 + jj) * NB + b]);
  *(bf16x8*)(tvf + (long)t * 8) = v;
}

// ---------------------------------------------------------------------------
// Gather embeddings -> emb[e][b][k] fp32 (R4's proven kernel)
__global__ void k_gather(const int* __restrict__ pos_u,
                         const int* __restrict__ pos_v,
                         const int* __restrict__ neg_v,
                         const float* __restrict__ U,
                         const float* __restrict__ V,
                         float* __restrict__ emb) {
  const int be = blockIdx.x;
  const int b = be / NE, e = be % NE;
  const float* src;
  if (e == 0)      src = U + (long)pos_u[b] * DD3;
  else if (e == 1) src = V + (long)pos_v[b] * DD3;
  else             src = V + (long)neg_v[b * 5 + (e - 2)] * DD3;
  const float4 v = ((const float4*)src)[threadIdx.x];
  ((float4*)(emb + ((long)e * NB + b) * DD3))[threadIdx.x] = v;
}

// ---------------------------------------------------------------------------
__global__ __launch_bounds__(1024) void k_gram(const float* __restrict__ W4,
                                               const float* __restrict__ b4,
                                               float* __restrict__ G,
                                               float* __restrict__ gv) {
  const int p = blockIdx.x, t = threadIdx.x;
  const int q = t & 255, nq = t >> 8;
  __shared__ float colp[DD3];
  __shared__ float red[4][257];
  __shared__ float gred[4];
  for (int n = t; n < DD3; n += 1024) colp[n] = W4[n * DD + p];
  __syncthreads();
  float acc = 0.f;
  const int n0 = nq * 192;
#pragma unroll 8
  for (int n = n0; n < n0 + 192; ++n) acc = fmaf(colp[n], W4[n * DD + q], acc);
  red[nq][q] = acc;
  float gp = 0.f;
  for (int n = n0; n < n0 + 192; ++n) gp = fmaf(b4[n], colp[n], gp);
  if (q == 0) gred[nq] = gp;
  __syncthreads();
  if (t < 256) G[p * DD + t] = red[0][t] + red[1][t] + red[2][t] + red[3][t];
  if (t == 0) gv[p] = gred[0] + gred[1] + gred[2] + gred[3];
}

// ---------------------------------------------------------------------------
// Repack T (fp32, [i][j][k]) -> Tf (bf16 A-fragments, lane-final order).
// UNCHANGED (proven ~5 TB/s).
__global__ __launch_bounds__(512) void k_repack(const float* __restrict__ T,
                                                short* __restrict__ Tf) {
  __shared__ float Ls[16 * 772];
  const int it = blockIdx.x >> 7;
  const int jp = blockIdx.x & 127;
  const int j0 = jp * 2;
  const int t = threadIdx.x;
  const int w = t >> 6, lane = t & 63;

#pragma unroll 1
  for (int l4 = 0; l4 < 4; ++l4) {
    const int i = it * 32 + l4 * 8 + w;
    float4 v[2][3];
#pragma unroll
    for (int jl = 0; jl < 2; ++jl) {
      const float4* src = (const float4*)(T + (long)i * 196608 + (j0 + jl) * 768);
#pragma unroll
      for (int c = 0; c < 3; ++c) v[jl][c] = src[c * 64 + lane];
    }
#pragma unroll
    for (int jl = 0; jl < 2; ++jl) {
      const int row = w * 2 + jl;
#pragma unroll
      for (int c = 0; c < 3; ++c)
        *(float4*)&Ls[row * 772 + (c * 64 + lane) * 4] = v[jl][c];
    }
    __syncthreads();
#pragma unroll
    for (int q = 0; q < 3; ++q) {
      const int F = t + 512 * q;
      const int l15 = F & 15;
      const int mf = (F >> 4) & 3;
      const int mh = (F >> 6) & 1;
      const int jc = F >> 7;
      const int kc = jc % 6;
      const int jl = jc / 6;
      const int k = kc * 128 + mh * 64 + mf * 16 + l15;
      bf16x8 o;
#pragma unroll
      for (int jj = 0; jj < 8; ++jj)
        o[jj] = (short)bf16rne(Ls[(jj * 2 + jl) * 772 + k]);
      const long FI = (long)(j0 + jl) * 24576 + kc * 4096 + it * 512 +
                      mh * 256 + mf * 64 + l4 * 16 + l15;
      *(bf16x8*)(Tf + FI * 8) = o;
    }
    __syncthreads();
  }
}

// ---------------------------------------------------------------------------
// Main kernel v3: grid 3072 = (kcm 0..11) x (j 0..255); kc = kcm>>1, mh = kcm&1.
// 256-thread blocks (4 waves = 4 bq), NO LDS, NO barriers, no mh-reduce.
// Per wave: depth-2 Tf register prefetch + 8 MFMA/it; epilogue float4 emb loads
// (56 instr/thread); per-wave shfl reduce over l4; atomicAdd into h3.
__global__ __launch_bounds__(256, 4) void k_main_f(const short* __restrict__ Tf,
                                                   const short* __restrict__ tvf,
                                                   const float* __restrict__ emb,
                                                   const float* __restrict__ tvB,
                                                   float* __restrict__ h3) {
  const int bid = blockIdx.x;
  const int j = bid & 255;
  const int kcm = bid >> 8;          // 0..11
  const int kc = kcm >> 1;
  const int mh = kcm & 1;

  const int t = threadIdx.x;
  const int l = t & 63;
  const int bq = t >> 6;             // 0..3 (32 b each)
  const int l15 = l & 15;
  const int l4 = (l >> 4) & 3;

  const bf16x8* fr  = (const bf16x8*)Tf + ((long)j * 24576 + kc * 4096 + mh * 256 + l);
  const bf16x8* tvp = (const bf16x8*)tvf + l;

  f32x4 acc[4][2];
#pragma unroll
  for (int mf = 0; mf < 4; ++mf) {
    acc[mf][0] = {0.f, 0.f, 0.f, 0.f};
    acc[mf][1] = {0.f, 0.f, 0.f, 0.f};
  }

  bf16x8 afb[2][4];
  bf16x8 tvb[2][2];
#pragma unroll
  for (int mf = 0; mf < 4; ++mf) afb[0][mf] = fr[mf * 64];
#pragma unroll
  for (int nf = 0; nf < 2; ++nf) tvb[0][nf] = tvp[((bq * 2 + nf) * 8) * 64];

#pragma unroll
  for (int it = 0; it < 8; ++it) {
    const int cur = it & 1, nxt = cur ^ 1;
    if (it < 7) {
#pragma unroll
      for (int mf = 0; mf < 4; ++mf) afb[nxt][mf] = fr[(it + 1) * 512 + mf * 64];
#pragma unroll
      for (int nf = 0; nf < 2; ++nf) tvb[nxt][nf] = tvp[((bq * 2 + nf) * 8 + it + 1) * 64];
    }
#pragma unroll
    for (int mf = 0; mf < 4; ++mf) {
      acc[mf][0] = __builtin_amdgcn_mfma_f32_16x16x32_bf16(afb[cur][mf], tvb[cur][0], acc[mf][0], 0, 0, 0);
      acc[mf][1] = __builtin_amdgcn_mfma_f32_16x16x32_bf16(afb[cur][mf], tvb[cur][1], acc[mf][1], 0, 0, 0);
    }
  }

  // Epilogue: lane's acc[mf][nf][q] covers 4 CONSECUTIVE k -> one float4 per (mf,nf,e).
  float h3p[NE][2];
#pragma unroll
  for (int e = 0; e < NE; ++e) { h3p[e][0] = 0.f; h3p[e][1] = 0.f; }

  const long kbase = (long)(kc * 128 + mh * 64 + l4 * 4);
#pragma unroll
  for (int mf = 0; mf < 4; ++mf) {
#pragma unroll
    for (int nf = 0; nf < 2; ++nf) {
      const int b = bq * 32 + nf * 16 + l15;
      const float* ep = emb + (long)b * DD3 + kbase + mf * 16;
#pragma unroll
      for (int e = 0; e < NE; ++e) {
        const f32x4 em = *(const f32x4*)(ep + (long)e * (NB * DD3));
        float s = h3p[e][nf];
        s = fmaf(acc[mf][nf][0], em[0], s);
        s = fmaf(acc[mf][nf][1], em[1], s);
        s = fmaf(acc[mf][nf][2], em[2], s);
        s = fmaf(acc[mf][nf][3], em[3], s);
        h3p[e][nf] = s;
      }
    }
  }

  // Reduce over the 4 l4 quads (lanes l15, l15+16, l15+32, l15+48)
#pragma unroll
  for (int e = 0; e < NE; ++e)
#pragma unroll
    for (int nf = 0; nf < 2; ++nf) {
      float v = h3p[e][nf];
      v += __shfl_xor(v, 16);
      v += __shfl_xor(v, 32);
      h3p[e][nf] = v;
    }
  if (l < 16) {
#pragma unroll
    for (int nf = 0; nf < 2; ++nf) {
      const int b = bq * 32 + nf * 16 + l;
      const float tb = (kcm == 0) ? tvB[b * DD + j] : 0.f;
#pragma unroll
      for (int e = 0; e < NE; ++e)
        atomicAdd(&h3[((long)b * NE + e) * DD + j], h3p[e][nf] + tb);
    }
  }
}

// ---------------------------------------------------------------------------
__global__ void k_score(const float* __restrict__ h3,
                        const float* __restrict__ G,
                        const float* __restrict__ gv,
                        const float* __restrict__ b4,
                        float* __restrict__ scoreb,
                        float* __restrict__ negb) {
  const int b = blockIdx.x, t = threadIdx.x;
  __shared__ float h3s[NE * DD];
  __shared__ float red[4][16];
  for (int idx = t; idx < NE * DD; idx += 256) h3s[idx] = h3[(long)b * NE * DD + idx];
  __syncthreads();
  float racc = 0.f;
#pragma unroll 8
  for (int jp = 0; jp < DD; ++jp) racc = fmaf(G[jp * DD + t], h3s[jp], racc);

  float loc[14];
#pragma unroll
  for (int e = 1; e < NE; ++e) loc[e - 1] = racc * h3s[e * DD + t];
  loc[6] = gv[t] * h3s[t];
#pragma unroll
  for (int e = 1; e < NE; ++e) loc[6 + e] = gv[t] * h3s[e * DD + t];
  loc[13] = b4[t] * b4[t] + b4[t + 256] * b4[t + 256] + b4[t + 512] * b4[t + 512];

  const int lane = t & 63, wid = t >> 6;
#pragma unroll
  for (int qd = 0; qd < 14; ++qd) {
    float v = loc[qd];
#pragma unroll
    for (int m = 1; m < 64; m <<= 1) v += __shfl_xor(v, m);
    if (lane == 0) red[wid][qd] = v;
  }
  __syncthreads();
  if (t == 0) {
    float r[14];
#pragma unroll
    for (int qd = 0; qd < 14; ++qd)
      r[qd] = red[0][qd] + red[1][qd] + red[2][qd] + red[3][qd];
    const float c = r[13], gu = r[6];
    auto logsig = [](float x) { return fminf(x, 0.f) - log1pf(expf(-fabsf(x))); };
    float dv = r[0] + gu + r[7] + c;
    dv = fminf(fmaxf(dv, -10.f), 10.f);
    const float sc = -logsig(dv);
    float ns = 0.f;
    for (int lx = 1; lx < 6; ++lx) {
      float dn = r[lx] + gu + r[7 + lx] + c;
      dn = fminf(fmaxf(dn, -10.f), 10.f);
      ns -= logsig(-dn);
    }
    scoreb[b] = sc;
    negb[b] = ns * 0.2f;
  }
}

// ---------------------------------------------------------------------------
__global__ void k_final(const float* __restrict__ scoreb,
                        const float* __restrict__ negb,
                        float* __restrict__ out) {
  const int t = threadIdx.x;
  float s = scoreb[t], n = negb[t];
#pragma unroll
  for (int m = 1; m < 64; m <<= 1) {
    s += __shfl_xor(s, m);
    n += __shfl_xor(n, m);
  }
  __shared__ float rs[2], rn[2];
  if ((t & 63) == 0) { rs[t >> 6] = s; rn[t >> 6] = n; }
  __syncthreads();
  if (t == 0) {
    const float S = (rs[0] + rs[1]) * (1.0f / 128.0f);
    const float N = (rn[0] + rn[1]) * (1.0f / 128.0f);
    out[0] = S + N;
    out[1] = S;
    out[2] = N;
  }
}

// ---------------------------------------------------------------------------
extern "C" void kernel_launch(void* const* d_in, const int* in_sizes, int n_in,
                              void* d_out, int out_size, void* d_ws, size_t ws_size,
                              hipStream_t stream) {
  const int*   pos_u = (const int*)d_in[0];
  const int*   pos_v = (const int*)d_in[1];
  const int*   neg_v = (const int*)d_in[2];
  const float* timev = (const float*)d_in[3];
  const float* m1    = (const float*)d_in[4];
  const float* b1    = (const float*)d_in[5];
  const float* W2    = (const float*)d_in[6];
  const float* b2    = (const float*)d_in[7];
  const float* W4    = (const float*)d_in[8];
  const float* b4    = (const float*)d_in[9];
  const float* U     = (const float*)d_in[10];
  const float* V     = (const float*)d_in[11];
  const float* T     = (const float*)d_in[12];
  const float* Bm    = (const float*)d_in[13];

  float* ws     = (float*)d_ws;
  float* tv_t   = ws + OFF_TVT;
  float* tvB    = ws + OFF_TVB;
  float* emb    = ws + OFF_EMB;
  float* h3     = ws + OFF_H3;
  float* G      = ws + OFF_G;
  float* gv     = ws + OFF_GV;
  short* tvf    = (short*)(ws + OFF_SC);
  short* Tf     = (short*)(ws + OFF_TF);
  float* scoreb = ws + OFF_SC;
  float* negb   = ws + OFF_SC + 128;
  float* out    = (float*)d_out;

  hipMemsetAsync(h3, 0, (size_t)NB * NE * DD * sizeof(float), stream);
  k_setup<<<128, 256, 0, stream>>>(timev, m1, b1, W2, b2, Bm, tv_t, tvB);
  k_pack<<<16, 256, 0, stream>>>(tv_t, tvf);
  k_gather<<<896, 192, 0, stream>>>(pos_u, pos_v, neg_v, U, V, emb);
  k_gram<<<256, 1024, 0, stream>>>(W4, b4, G, gv);
  k_repack<<<1024, 512, 0, stream>>>(T, Tf);
  k_main_f<<<3072, 256, 0, stream>>>(Tf, tvf, emb, tvB, h3);
  k_score<<<128, 256, 0, stream>>>(h3, G, gv, b4, scoreb, negb);
  k_final<<<1, 128, 0, stream>>>(scoreb, negb, out);
}

// Round 10
// 216.635 us; speedup vs baseline: 1.5439x; 1.4168x over previous
//
#include <hip/hip_runtime.h>
#include <hip/hip_bf16.h>

// Problem constants
#define DD   256
#define DD3  768
#define NB   128
#define NE   7      // 1 pos_u + 1 pos_v + 5 neg embeddings

// Workspace layout (float offsets)
#define OFF_TVT  0u          // tv transposed [256 i][128 b]
#define OFF_TVB  32768u      // tvB [128 b][256 j]
#define OFF_EMB  65536u      // emb [7 e][128 b][768 k] fp32
#define OFF_H3   753664u     // h3  [128 b][7 e][256 j]  (plain stores, fully overwritten)
#define OFF_G    983040u     // G = W4^T W4 [256][256]
#define OFF_GV   1048576u    // g = W4^T b4 [256]
#define OFF_SC   1048832u    // tvf (bf16 frags) aliased with scoreb/negb (tvf dead by k_score)
#define OFF_TF   1065216u    // Tf bf16 A-fragments (100.7 MB); ws proven >= 105 MB (R7-R9 ran this)

// Fragment linear index: FI = j*24576 + kc*4096 + it*512 + mh*256 + mf*64 + l
// Frag content: lane l, elem jj (bf16x8) = T[i = it*32 + (l>>4)*8 + jj][j][k = kc*128 + mh*64 + mf*16 + (l&15)]

typedef __attribute__((ext_vector_type(8))) short bf16x8;
typedef __attribute__((ext_vector_type(4))) float f32x4;

__device__ __forceinline__ unsigned bf16rne(float f) {
  unsigned u = __float_as_uint(f);
  return (u + 0x7fffu + ((u >> 16) & 1u)) >> 16;   // round-to-nearest-even
}

// ---------------------------------------------------------------------------
__global__ void k_setup(const float* __restrict__ timev,
                        const float* __restrict__ m1,
                        const float* __restrict__ b1,
                        const float* __restrict__ W2,
                        const float* __restrict__ b2,
                        const float* __restrict__ Bm,
                        float* __restrict__ tv_t,
                        float* __restrict__ tvB) {
  const int b = blockIdx.x, i = threadIdx.x;
  __shared__ float h1[DD];
  __shared__ float tvs[DD];
  const float t = timev[b] * (1.0f / 20.0f);
  h1[i] = tanhf(fmaf(t, m1[i], b1[i]));
  __syncthreads();
  float acc = b2[i];
  const float* w2r = W2 + i * DD;
#pragma unroll 8
  for (int jj = 0; jj < DD; ++jj) acc = fmaf(h1[jj], w2r[jj], acc);
  const float tvi = tanhf(acc);
  tvs[i] = tvi;
  tv_t[i * NB + b] = tvi;
  __syncthreads();
  float a2 = 0.f;
#pragma unroll 8
  for (int ii = 0; ii < DD; ++ii) a2 = fmaf(tvs[ii], Bm[ii * DD + i], a2);
  tvB[b * DD + i] = a2;
}

// ---------------------------------------------------------------------------
// Pack tv into bf16 MFMA B-fragments: frag f = bf*8+it (bf = b-frag 0..7)
__global__ void k_pack(const float* __restrict__ tv_t, short* __restrict__ tvf) {
  const int t = blockIdx.x * 256 + threadIdx.x;   // 4096 threads
  const int f = t >> 6, l = t & 63;
  const int b = (f >> 3) * 16 + (l & 15);
  const int i0 = (f & 7) * 32 + ((l >> 4) & 3) * 8;
  bf16x8 v;
#pragma unroll
  for (int jj = 0; jj < 8; ++jj)
    v[jj] = (short)bf16rne(tv_t[(i0 + jj) * NB + b]);
  *(bf16x8*)(tvf + (long)t * 8) = v;
}

// ---------------------------------------------------------------------------
// Gather embeddings -> emb[e][b][k] fp32
__global__ void k_gather(const int* __restrict__ pos_u,
                         const int* __restrict__ pos_v,
                         const int* __restrict__ neg_v,
                         const float* __restrict__ U,
                         const float* __restrict__ V,
                         float* __restrict__ emb) {
  const int be = blockIdx.x;
  const int b = be / NE, e = be % NE;
  const float* src;
  if (e == 0)      src = U + (long)pos_u[b] * DD3;
  else if (e == 1) src = V + (long)pos_v[b] * DD3;
  else             src = V + (long)neg_v[b * 5 + (e - 2)] * DD3;
  const float4 v = ((const float4*)src)[threadIdx.x];
  ((float4*)(emb + ((long)e * NB + b) * DD3))[threadIdx.x] = v;
}

// ---------------------------------------------------------------------------
__global__ __launch_bounds__(1024) void k_gram(const float* __restrict__ W4,
                                               const float* __restrict__ b4,
                                               float* __restrict__ G,
                                               float* __restrict__ gv) {
  const int p = blockIdx.x, t = threadIdx.x;
  const int q = t & 255, nq = t >> 8;
  __shared__ float colp[DD3];
  __shared__ float red[4][257];
  __shared__ float gred[4];
  for (int n = t; n < DD3; n += 1024) colp[n] = W4[n * DD + p];
  __syncthreads();
  float acc = 0.f;
  const int n0 = nq * 192;
#pragma unroll 8
  for (int n = n0; n < n0 + 192; ++n) acc = fmaf(colp[n], W4[n * DD + q], acc);
  red[nq][q] = acc;
  float gp = 0.f;
  for (int n = n0; n < n0 + 192; ++n) gp = fmaf(b4[n], colp[n], gp);
  if (q == 0) gred[nq] = gp;
  __syncthreads();
  if (t < 256) G[p * DD + t] = red[0][t] + red[1][t] + red[2][t] + red[3][t];
  if (t == 0) gv[p] = gred[0] + gred[1] + gred[2] + gred[3];
}

// ---------------------------------------------------------------------------
// Repack T (fp32, [i][j][k]) -> Tf (bf16 A-fragments, lane-final order).
// UNCHANGED (proven ~5 TB/s).
__global__ __launch_bounds__(512) void k_repack(const float* __restrict__ T,
                                                short* __restrict__ Tf) {
  __shared__ float Ls[16 * 772];
  const int it = blockIdx.x >> 7;
  const int jp = blockIdx.x & 127;
  const int j0 = jp * 2;
  const int t = threadIdx.x;
  const int w = t >> 6, lane = t & 63;

#pragma unroll 1
  for (int l4 = 0; l4 < 4; ++l4) {
    const int i = it * 32 + l4 * 8 + w;
    float4 v[2][3];
#pragma unroll
    for (int jl = 0; jl < 2; ++jl) {
      const float4* src = (const float4*)(T + (long)i * 196608 + (j0 + jl) * 768);
#pragma unroll
      for (int c = 0; c < 3; ++c) v[jl][c] = src[c * 64 + lane];
    }
#pragma unroll
    for (int jl = 0; jl < 2; ++jl) {
      const int row = w * 2 + jl;
#pragma unroll
      for (int c = 0; c < 3; ++c)
        *(float4*)&Ls[row * 772 + (c * 64 + lane) * 4] = v[jl][c];
    }
    __syncthreads();
#pragma unroll
    for (int q = 0; q < 3; ++q) {
      const int F = t + 512 * q;
      const int l15 = F & 15;
      const int mf = (F >> 4) & 3;
      const int mh = (F >> 6) & 1;
      const int jc = F >> 7;
      const int kc = jc % 6;
      const int jl = jc / 6;
      const int k = kc * 128 + mh * 64 + mf * 16 + l15;
      bf16x8 o;
#pragma unroll
      for (int jj = 0; jj < 8; ++jj)
        o[jj] = (short)bf16rne(Ls[(jj * 2 + jl) * 772 + k]);
      const long FI = (long)(j0 + jl) * 24576 + kc * 4096 + it * 512 +
                      mh * 256 + mf * 64 + l4 * 16 + l15;
      *(bf16x8*)(Tf + FI * 8) = o;
    }
    __syncthreads();
  }
}

// ---------------------------------------------------------------------------
// Main kernel v4: grid 512 = 256 j x 2 bh (64-batch halves). ZERO atomics.
// XCD co-location: xcd = bid&7, slot = bid>>3 -> j = xcd*32 + (slot>>1),
// bh = slot&1 (the (j,bh) pair shares Tf column in its XCD's L2).
// 8 waves = 4 bq (16 b) x 2 mh (64 k of each 128-chunk). In-block kc loop
// 0..5, register accumulation of h3p across kc; depth-2 Tf register prefetch;
// epilogue float4 emb loads; final cross-mh LDS reduce + PLAIN stores.
__global__ __launch_bounds__(512, 4) void k_main_f(const short* __restrict__ Tf,
                                                   const short* __restrict__ tvf,
                                                   const float* __restrict__ emb,
                                                   const float* __restrict__ tvB,
                                                   float* __restrict__ h3) {
  __shared__ float h3red[64][NE];
  const int bid = blockIdx.x;
  const int xcd = bid & 7, slot = bid >> 3;
  const int j = xcd * 32 + (slot >> 1);
  const int bh = slot & 1;

  const int t = threadIdx.x;
  const int l = t & 63;
  const int w = t >> 6;
  const int bq = w >> 1;             // 0..3 (16 b each)
  const int mh = w & 1;              // k-half of each 128-k chunk
  const int l15 = l & 15;
  const int l4 = (l >> 4) & 3;

  // Preload tv B-fragments for this wave's 16 b (bf = bh*4 + bq)
  const int bf = bh * 4 + bq;
  bf16x8 tvfr[8];
#pragma unroll
  for (int it = 0; it < 8; ++it)
    tvfr[it] = *(const bf16x8*)(tvf + (((bf * 8) + it) * 64 + l) * 8);

  // Tf fragment base for (j, mh, lane); per (kc,it,mf): + kc*4096 + it*512 + mf*64
  const bf16x8* fr = (const bf16x8*)Tf + ((long)j * 24576 + mh * 256 + l);

  float h3p[NE];
#pragma unroll
  for (int e = 0; e < NE; ++e) h3p[e] = 0.f;

  bf16x8 afb[2][4];
#pragma unroll
  for (int mf = 0; mf < 4; ++mf) afb[0][mf] = fr[mf * 64];   // kc=0, it=0

#pragma unroll 1
  for (int kc = 0; kc < 6; ++kc) {
    f32x4 acc[4];
#pragma unroll
    for (int mf = 0; mf < 4; ++mf) acc[mf] = {0.f, 0.f, 0.f, 0.f};

#pragma unroll
    for (int it = 0; it < 8; ++it) {
      const int cur = it & 1, nxt = cur ^ 1;
      if (it < 7) {
#pragma unroll
        for (int mf = 0; mf < 4; ++mf)
          afb[nxt][mf] = fr[kc * 4096 + (it + 1) * 512 + mf * 64];
      } else if (kc < 5) {
#pragma unroll
        for (int mf = 0; mf < 4; ++mf)
          afb[nxt][mf] = fr[(kc + 1) * 4096 + mf * 64];
      }
#pragma unroll
      for (int mf = 0; mf < 4; ++mf)
        acc[mf] = __builtin_amdgcn_mfma_f32_16x16x32_bf16(afb[cur][mf], tvfr[it], acc[mf], 0, 0, 0);
    }

    // Epilogue for this kc: lane's acc[mf][q] = 4 consecutive k -> float4 emb loads.
    const int b = bh * 64 + bq * 16 + l15;
    const float* ep = emb + (long)b * DD3 + kc * 128 + mh * 64 + l4 * 4;
#pragma unroll
    for (int mf = 0; mf < 4; ++mf) {
#pragma unroll
      for (int e = 0; e < NE; ++e) {
        const f32x4 em = *(const f32x4*)(ep + (long)e * (NB * DD3) + mf * 16);
        float s = h3p[e];
        s = fmaf(acc[mf][0], em[0], s);
        s = fmaf(acc[mf][1], em[1], s);
        s = fmaf(acc[mf][2], em[2], s);
        s = fmaf(acc[mf][3], em[3], s);
        h3p[e] = s;
      }
    }
  }

  // Reduce over the 4 l4 quads, then cross-mh via LDS, then plain store.
#pragma unroll
  for (int e = 0; e < NE; ++e) {
    float v = h3p[e];
    v += __shfl_xor(v, 16);
    v += __shfl_xor(v, 32);
    h3p[e] = v;
  }
  __syncthreads();
  if (mh == 0 && l < 16) {
#pragma unroll
    for (int e = 0; e < NE; ++e) h3red[bq * 16 + l][e] = h3p[e];
  }
  __syncthreads();
  if (mh == 1 && l < 16) {
    const int bl = bq * 16 + l;
    const int b = bh * 64 + bl;
    const float tb = tvB[b * DD + j];
#pragma unroll
    for (int e = 0; e < NE; ++e)
      h3[((long)b * NE + e) * DD + j] = h3red[bl][e] + h3p[e] + tb;
  }
}

// ---------------------------------------------------------------------------
__global__ void k_score(const float* __restrict__ h3,
                        const float* __restrict__ G,
                        const float* __restrict__ gv,
                        const float* __restrict__ b4,
                        float* __restrict__ scoreb,
                        float* __restrict__ negb) {
  const int b = blockIdx.x, t = threadIdx.x;
  __shared__ float h3s[NE * DD];
  __shared__ float red[4][16];
  for (int idx = t; idx < NE * DD; idx += 256) h3s[idx] = h3[(long)b * NE * DD + idx];
  __syncthreads();
  float racc = 0.f;
#pragma unroll 8
  for (int jp = 0; jp < DD; ++jp) racc = fmaf(G[jp * DD + t], h3s[jp], racc);

  float loc[14];
#pragma unroll
  for (int e = 1; e < NE; ++e) loc[e - 1] = racc * h3s[e * DD + t];
  loc[6] = gv[t] * h3s[t];
#pragma unroll
  for (int e = 1; e < NE; ++e) loc[6 + e] = gv[t] * h3s[e * DD + t];
  loc[13] = b4[t] * b4[t] + b4[t + 256] * b4[t + 256] + b4[t + 512] * b4[t + 512];

  const int lane = t & 63, wid = t >> 6;
#pragma unroll
  for (int qd = 0; qd < 14; ++qd) {
    float v = loc[qd];
#pragma unroll
    for (int m = 1; m < 64; m <<= 1) v += __shfl_xor(v, m);
    if (lane == 0) red[wid][qd] = v;
  }
  __syncthreads();
  if (t == 0) {
    float r[14];
#pragma unroll
    for (int qd = 0; qd < 14; ++qd)
      r[qd] = red[0][qd] + red[1][qd] + red[2][qd] + red[3][qd];
    const float c = r[13], gu = r[6];
    auto logsig = [](float x) { return fminf(x, 0.f) - log1pf(expf(-fabsf(x))); };
    float dv = r[0] + gu + r[7] + c;
    dv = fminf(fmaxf(dv, -10.f), 10.f);
    const float sc = -logsig(dv);
    float ns = 0.f;
    for (int lx = 1; lx < 6; ++lx) {
      float dn = r[lx] + gu + r[7 + lx] + c;
      dn = fminf(fmaxf(dn, -10.f), 10.f);
      ns -= logsig(-dn);
    }
    scoreb[b] = sc;
    negb[b] = ns * 0.2f;
  }
}

// ---------------------------------------------------------------------------
__global__ void k_final(const float* __restrict__ scoreb,
                        const float* __restrict__ negb,
                        float* __restrict__ out) {
  const int t = threadIdx.x;
  float s = scoreb[t], n = negb[t];
#pragma unroll
  for (int m = 1; m < 64; m <<= 1) {
    s += __shfl_xor(s, m);
    n += __shfl_xor(n, m);
  }
  __shared__ float rs[2], rn[2];
  if ((t & 63) == 0) { rs[t >> 6] = s; rn[t >> 6] = n; }
  __syncthreads();
  if (t == 0) {
    const float S = (rs[0] + rs[1]) * (1.0f / 128.0f);
    const float N = (rn[0] + rn[1]) * (1.0f / 128.0f);
    out[0] = S + N;
    out[1] = S;
    out[2] = N;
  }
}

// ---------------------------------------------------------------------------
extern "C" void kernel_launch(void* const* d_in, const int* in_sizes, int n_in,
                              void* d_out, int out_size, void* d_ws, size_t ws_size,
                              hipStream_t stream) {
  const int*   pos_u = (const int*)d_in[0];
  const int*   pos_v = (const int*)d_in[1];
  const int*   neg_v = (const int*)d_in[2];
  const float* timev = (const float*)d_in[3];
  const float* m1    = (const float*)d_in[4];
  const float* b1    = (const float*)d_in[5];
  const float* W2    = (const float*)d_in[6];
  const float* b2    = (const float*)d_in[7];
  const float* W4    = (const float*)d_in[8];
  const float* b4    = (const float*)d_in[9];
  const float* U     = (const float*)d_in[10];
  const float* V     = (const float*)d_in[11];
  const float* T     = (const float*)d_in[12];
  const float* Bm    = (const float*)d_in[13];

  float* ws     = (float*)d_ws;
  float* tv_t   = ws + OFF_TVT;
  float* tvB    = ws + OFF_TVB;
  float* emb    = ws + OFF_EMB;
  float* h3     = ws + OFF_H3;
  float* G      = ws + OFF_G;
  float* gv     = ws + OFF_GV;
  short* tvf    = (short*)(ws + OFF_SC);
  short* Tf     = (short*)(ws + OFF_TF);
  float* scoreb = ws + OFF_SC;
  float* negb   = ws + OFF_SC + 128;
  float* out    = (float*)d_out;

  k_setup<<<128, 256, 0, stream>>>(timev, m1, b1, W2, b2, Bm, tv_t, tvB);
  k_pack<<<16, 256, 0, stream>>>(tv_t, tvf);
  k_gather<<<896, 192, 0, stream>>>(pos_u, pos_v, neg_v, U, V, emb);
  k_gram<<<256, 1024, 0, stream>>>(W4, b4, G, gv);
  k_repack<<<1024, 512, 0, stream>>>(T, Tf);
  k_main_f<<<512, 512, 0, stream>>>(Tf, tvf, emb, tvB, h3);
  k_score<<<128, 256, 0, stream>>>(h3, G, gv, b4, scoreb, negb);
  k_final<<<1, 128, 0, stream>>>(scoreb, negb, out);
}